// Round 2
// baseline (187.887 us; speedup 1.0000x reference)
//
#include <hip/hip_runtime.h>

// Attention fwd with materialized p_attn.
// B=16, S=2048, D=64, f32 in/out. d_out = [out (B,S,D) | p_attn (B,S,S)] f32.
#define BN 16
#define SN 2048
#define DN 64
#define QB 16           // q rows per block
#define NWAVE 4
#define KSEG (SN / NWAVE)   // 512 keys per wave
#define SROW 2056       // bf16 elems per LDS score row (pad -> 16B-aligned stride)

typedef __attribute__((ext_vector_type(8))) short bf16x8;
typedef __attribute__((ext_vector_type(4))) short bf16x4;
typedef __attribute__((ext_vector_type(4))) float f32x4;

static __device__ __forceinline__ short f2bf(float f) {
    union { float f; unsigned u; } v; v.f = f;
    unsigned r = v.u + 0x7fffu + ((v.u >> 16) & 1u);   // round-to-nearest-even
    return (short)(r >> 16);
}
static __device__ __forceinline__ float bf2f(short s) {
    union { unsigned u; float f; } v; v.u = ((unsigned)(unsigned short)s) << 16;
    return v.f;
}

__global__ __launch_bounds__(256, 2)
void attn_fused(const float* __restrict__ Q, const float* __restrict__ K,
                const float* __restrict__ V, const int* __restrict__ M,
                float* __restrict__ out)
{
    __shared__ short sbuf[QB * SROW];        // scores / p' (bf16 bits), later reused for O reduce
    __shared__ float mred[NWAVE * QB];
    __shared__ float lred[NWAVE * QB];
    __shared__ float lfin[QB];

    const int tid = threadIdx.x;
    const int wv = tid >> 6, ln = tid & 63;
    const int lq = ln & 15, lg = ln >> 4;

    const int bb = blockIdx.x >> 7;          // batch
    const int q0 = (blockIdx.x & 127) << 4;  // q-tile base

    const float* Qb = Q + ((size_t)bb * SN + q0) * DN;
    const float* Kb = K + (size_t)bb * SN * DN;
    const float* Vb = V + (size_t)bb * SN * DN;
    const int*   Mb = M + (size_t)bb * SN;
    float* out_o = out + ((size_t)bb * SN + q0) * DN;
    float* out_p = out + (size_t)BN * SN * DN + ((size_t)bb * SN + q0) * SN;

    // ---- Q fragments (A-operand, rows = q, k = d), held all kernel ----
    bf16x8 qf[2];
    #pragma unroll
    for (int s = 0; s < 2; ++s) {
        const float* src = Qb + lq * DN + s * 32 + lg * 8;
        #pragma unroll
        for (int j = 0; j < 8; ++j) qf[s][j] = f2bf(src[j]);
    }

    const int k0 = wv * KSEG;

    // ---- pass 1: S = QK^T * scale, masked -> LDS (bf16); per-row max ----
    float lmax[4] = {-3e38f, -3e38f, -3e38f, -3e38f};
    for (int kb = k0; kb < k0 + KSEG; kb += 16) {
        const float* ksrc = Kb + (size_t)(kb + lq) * DN + lg * 8;
        bf16x8 kf0, kf1;
        #pragma unroll
        for (int j = 0; j < 8; ++j) { kf0[j] = f2bf(ksrc[j]); kf1[j] = f2bf(ksrc[32 + j]); }
        f32x4 acc = {0.f, 0.f, 0.f, 0.f};
        acc = __builtin_amdgcn_mfma_f32_16x16x32_bf16(qf[0], kf0, acc, 0, 0, 0);
        acc = __builtin_amdgcn_mfma_f32_16x16x32_bf16(qf[1], kf1, acc, 0, 0, 0);
        const int mv = Mb[kb + lq];
        #pragma unroll
        for (int r = 0; r < 4; ++r) {
            float s = mv ? acc[r] * 0.125f : -1e9f;
            short sb = f2bf(s);
            lmax[r] = fmaxf(lmax[r], bf2f(sb));   // max over ROUNDED scores -> exp(s-m)<=1 always
            sbuf[(4 * lg + r) * SROW + kb + lq] = sb;
        }
    }
    #pragma unroll
    for (int r = 0; r < 4; ++r) {
        lmax[r] = fmaxf(lmax[r], __shfl_xor(lmax[r], 1));
        lmax[r] = fmaxf(lmax[r], __shfl_xor(lmax[r], 2));
        lmax[r] = fmaxf(lmax[r], __shfl_xor(lmax[r], 4));
        lmax[r] = fmaxf(lmax[r], __shfl_xor(lmax[r], 8));
    }
    if (lq == 0) {
        #pragma unroll
        for (int r = 0; r < 4; ++r) mred[wv * QB + 4 * lg + r] = lmax[r];
    }
    __syncthreads();

    const float mrow = fmaxf(fmaxf(mred[lq], mred[QB + lq]),
                             fmaxf(mred[2 * QB + lq], mred[3 * QB + lq]));

    // ---- pass 2: p' = exp(s-m) -> LDS; row sums; O += p' V ----
    f32x4 oacc[4];
    #pragma unroll
    for (int nt = 0; nt < 4; ++nt) oacc[nt] = (f32x4){0.f, 0.f, 0.f, 0.f};
    float lsum = 0.f;
    for (int kb = k0; kb < k0 + KSEG; kb += 32) {
        short* sp = &sbuf[lq * SROW + kb + 8 * lg];
        bf16x8 sf = *(const bf16x8*)sp;
        bf16x8 pf;
        #pragma unroll
        for (int j = 0; j < 8; ++j) {
            float p = exp2f((bf2f(sf[j]) - mrow) * 1.4426950408889634f);
            lsum += p;
            pf[j] = f2bf(p);
        }
        *(bf16x8*)sp = pf;   // stash unnormalized p' (same lane, same addr)
        #pragma unroll
        for (int nt = 0; nt < 4; ++nt) {
            const float* vsrc = Vb + (size_t)(kb + 8 * lg) * DN + nt * 16 + lq;
            bf16x8 vf;
            #pragma unroll
            for (int j = 0; j < 8; ++j) vf[j] = f2bf(vsrc[(size_t)j * DN]);
            oacc[nt] = __builtin_amdgcn_mfma_f32_16x16x32_bf16(pf, vf, oacc[nt], 0, 0, 0);
        }
    }
    lsum += __shfl_xor(lsum, 16);
    lsum += __shfl_xor(lsum, 32);
    if (lg == 0) lred[wv * QB + lq] = lsum;
    __syncthreads();
    if (tid < QB)
        lfin[tid] = 1.f / (lred[tid] + lred[QB + tid] + lred[2 * QB + tid] + lred[3 * QB + tid]);
    __syncthreads();

    // ---- pass 3: stream p_attn = p'/l to global (coalesced float4 NT stores) ----
    #pragma unroll 1
    for (int q = 0; q < QB; ++q) {
        const float rl = lfin[q];
        #pragma unroll
        for (int i = 0; i < 2; ++i) {
            const int c4 = tid + i * 256;
            bf16x4 s4 = *(const bf16x4*)&sbuf[q * SROW + c4 * 4];
            f32x4 o;
            o[0] = bf2f(s4[0]) * rl; o[1] = bf2f(s4[1]) * rl;
            o[2] = bf2f(s4[2]) * rl; o[3] = bf2f(s4[3]) * rl;
            __builtin_nontemporal_store(o, (f32x4*)&out_p[(size_t)q * SN + c4 * 4]);
        }
    }
    __syncthreads();

    // ---- cross-wave O reduce (reuse sbuf memory), normalize, write ----
    float* obuf = (float*)sbuf;
    #pragma unroll
    for (int nt = 0; nt < 4; ++nt) {
        #pragma unroll
        for (int r = 0; r < 4; ++r)
            obuf[(wv * QB + 4 * lg + r) * DN + nt * 16 + lq] = oacc[nt][r];
    }
    __syncthreads();
    #pragma unroll
    for (int i = 0; i < 4; ++i) {
        const int idx = tid + i * 256;
        const int q = idx >> 6, d = idx & 63;
        float v = obuf[q * DN + d] + obuf[(QB + q) * DN + d] +
                  obuf[(2 * QB + q) * DN + d] + obuf[(3 * QB + q) * DN + d];
        __builtin_nontemporal_store(v * lfin[q], &out_o[(size_t)q * DN + d]);
    }
}

extern "C" void kernel_launch(void* const* d_in, const int* in_sizes, int n_in,
                              void* d_out, int out_size, void* d_ws, size_t ws_size,
                              hipStream_t stream) {
    const float* Q = (const float*)d_in[0];
    const float* K = (const float*)d_in[1];
    const float* V = (const float*)d_in[2];
    const int*   M = (const int*)d_in[3];
    float* out = (float*)d_out;
    dim3 grid(BN * (SN / QB));   // 16 * 128 = 2048 blocks
    dim3 block(256);
    attn_fused<<<grid, block, 0, stream>>>(Q, K, V, M, out);
}

// Round 3
// 151.483 us; speedup vs baseline: 1.2403x; 1.2403x over previous
//
#include <hip/hip_runtime.h>
#include <hip/hip_bf16.h>

// Attention fwd with materialized p_attn.
// B=16, S=2048, D=64, f32 in/out. d_out = [out (B,S,D) | p_attn (B,S,S)] f32.
#define BN 16
#define SN 2048
#define DN 64
#define QB 16             // q rows per block
#define NWAVE 8           // 512 threads
#define KSEG (SN / NWAVE) // 256 keys per wave
#define SROW 2056         // bf16 elems per LDS score row (pad -> 16B-aligned stride)

typedef __attribute__((ext_vector_type(8))) short bf16x8;
typedef __attribute__((ext_vector_type(4))) short bf16x4;
typedef __attribute__((ext_vector_type(4))) float f32x4;

static __device__ __forceinline__ short f2bf(float f) {
    __hip_bfloat16 h = __float2bfloat16(f);   // hardware RNE cvt
    union { __hip_bfloat16 h; short s; } u; u.h = h;
    return u.s;
}
static __device__ __forceinline__ float bf2f(short s) {
    union { unsigned u; float f; } v; v.u = ((unsigned)(unsigned short)s) << 16;
    return v.f;
}

// ---- prep: K -> bf16 [B][S][D], V -> bf16 transposed [B][D][S] (both in ws) ----
__global__ __launch_bounds__(256)
void prep_kv(const float* __restrict__ K, const float* __restrict__ V,
             short* __restrict__ Kp, short* __restrict__ Vt)
{
    __shared__ short vt[64][68];              // 64x64 tile, pad 4 (8B-aligned rows)
    const int b  = blockIdx.x >> 5;           // 32 tiles per batch
    const int s0 = (blockIdx.x & 31) << 6;
    const int tid = threadIdx.x;
    const int sr = tid >> 4;                  // 0..15
    const int dc = (tid & 15) << 2;           // 0,4,...,60
    const float* Kb = K + ((size_t)b * SN + s0) * DN;
    const float* Vb = V + ((size_t)b * SN + s0) * DN;
    short* Kpb = Kp + ((size_t)b * SN + s0) * DN;
    #pragma unroll
    for (int i = 0; i < 4; ++i) {
        const int s = sr + i * 16;
        f32x4 kv = *(const f32x4*)(Kb + (size_t)s * DN + dc);
        f32x4 vv = *(const f32x4*)(Vb + (size_t)s * DN + dc);
        bf16x4 k4, v4;
        #pragma unroll
        for (int j = 0; j < 4; ++j) { k4[j] = f2bf(kv[j]); v4[j] = f2bf(vv[j]); }
        *(bf16x4*)(Kpb + (size_t)s * DN + dc) = k4;
        *(bf16x4*)&vt[s][dc] = v4;
    }
    __syncthreads();
    const int d  = tid >> 2;                  // 0..63
    const int sg = (tid & 3) << 4;            // 0,16,32,48
    short* dst = Vt + ((size_t)b * DN + d) * SN + s0 + sg;
    bf16x8 w0, w1;
    #pragma unroll
    for (int j = 0; j < 8; ++j) { w0[j] = vt[sg + j][d]; w1[j] = vt[sg + 8 + j][d]; }
    *(bf16x8*)dst = w0;
    *(bf16x8*)(dst + 8) = w1;
}

// ---- fused attention; PRE=1 uses preconverted bf16 K / V^T from ws ----
template <int PRE>
__global__ __launch_bounds__(512, 2)
void attn_fused(const float* __restrict__ Q, const float* __restrict__ K,
                const float* __restrict__ V, const int* __restrict__ M,
                const short* __restrict__ Kp, const short* __restrict__ Vt,
                float* __restrict__ out)
{
    __shared__ short sbuf[QB * SROW];         // scores / p' (bf16 bits); later O reduce
    __shared__ float mred[NWAVE * QB];
    __shared__ float lred[NWAVE * QB];
    __shared__ float lfin[QB];

    const int tid = threadIdx.x;
    const int wv = tid >> 6, ln = tid & 63;
    const int lq = ln & 15, lg = ln >> 4;

    const int bb = blockIdx.x >> 7;           // batch
    const int q0 = (blockIdx.x & 127) << 4;   // q-tile base

    const float* Qb = Q + ((size_t)bb * SN + q0) * DN;
    const float* Kb = K + (size_t)bb * SN * DN;
    const float* Vb = V + (size_t)bb * SN * DN;
    const short* Kpb = Kp + (size_t)bb * SN * DN;
    const short* Vtb = Vt + (size_t)bb * DN * SN;
    const int*   Mb = M + (size_t)bb * SN;
    float* out_o = out + ((size_t)bb * SN + q0) * DN;
    float* out_p = out + (size_t)BN * SN * DN + ((size_t)bb * SN + q0) * SN;

    // ---- Q fragments (A-operand, rows = q, k = d) ----
    bf16x8 qf[2];
    #pragma unroll
    for (int s = 0; s < 2; ++s) {
        const float* src = Qb + lq * DN + s * 32 + lg * 8;
        #pragma unroll
        for (int j = 0; j < 8; ++j) qf[s][j] = f2bf(src[j]);
    }

    const int k0 = wv * KSEG;

    // ---- pass 1: S = QK^T * scale, masked -> LDS (bf16); per-row max ----
    float lmax[4] = {-3e38f, -3e38f, -3e38f, -3e38f};
    for (int kb = k0; kb < k0 + KSEG; kb += 16) {
        bf16x8 kf0, kf1;
        if constexpr (PRE) {
            const short* kr = Kpb + (size_t)(kb + lq) * DN + lg * 8;
            kf0 = *(const bf16x8*)kr;
            kf1 = *(const bf16x8*)(kr + 32);
        } else {
            const float* ksrc = Kb + (size_t)(kb + lq) * DN + lg * 8;
            #pragma unroll
            for (int j = 0; j < 8; ++j) { kf0[j] = f2bf(ksrc[j]); kf1[j] = f2bf(ksrc[32 + j]); }
        }
        f32x4 acc = {0.f, 0.f, 0.f, 0.f};
        acc = __builtin_amdgcn_mfma_f32_16x16x32_bf16(qf[0], kf0, acc, 0, 0, 0);
        acc = __builtin_amdgcn_mfma_f32_16x16x32_bf16(qf[1], kf1, acc, 0, 0, 0);
        const int mv = Mb[kb + lq];
        #pragma unroll
        for (int r = 0; r < 4; ++r) {
            float s = mv ? acc[r] * 0.125f : -1e9f;
            short sb = f2bf(s);
            lmax[r] = fmaxf(lmax[r], bf2f(sb));   // max over ROUNDED scores -> exp(s-m)<=1
            sbuf[(4 * lg + r) * SROW + kb + lq] = sb;
        }
    }
    #pragma unroll
    for (int r = 0; r < 4; ++r) {
        lmax[r] = fmaxf(lmax[r], __shfl_xor(lmax[r], 1));
        lmax[r] = fmaxf(lmax[r], __shfl_xor(lmax[r], 2));
        lmax[r] = fmaxf(lmax[r], __shfl_xor(lmax[r], 4));
        lmax[r] = fmaxf(lmax[r], __shfl_xor(lmax[r], 8));
    }
    if (lq == 0) {
        #pragma unroll
        for (int r = 0; r < 4; ++r) mred[wv * QB + 4 * lg + r] = lmax[r];
    }
    __syncthreads();

    float mrow = mred[lq];
    #pragma unroll
    for (int w = 1; w < NWAVE; ++w) mrow = fmaxf(mrow, mred[w * QB + lq]);

    // ---- pass 2: p' = exp(s-m) -> LDS; row sums; O += p' V ----
    f32x4 oacc[4];
    #pragma unroll
    for (int nt = 0; nt < 4; ++nt) oacc[nt] = (f32x4){0.f, 0.f, 0.f, 0.f};
    float lsum = 0.f;
    for (int kb = k0; kb < k0 + KSEG; kb += 32) {
        short* sp = &sbuf[lq * SROW + kb + 8 * lg];
        bf16x8 sf = *(const bf16x8*)sp;
        bf16x8 pf;
        #pragma unroll
        for (int j = 0; j < 8; ++j) {
            float p = exp2f((bf2f(sf[j]) - mrow) * 1.4426950408889634f);
            lsum += p;
            pf[j] = f2bf(p);
        }
        *(bf16x8*)sp = pf;   // stash unnormalized p'
        #pragma unroll
        for (int nt = 0; nt < 4; ++nt) {
            bf16x8 vf;
            if constexpr (PRE) {
                vf = *(const bf16x8*)(Vtb + (size_t)(nt * 16 + lq) * SN + kb + 8 * lg);
            } else {
                const float* vsrc = Vb + (size_t)(kb + 8 * lg) * DN + nt * 16 + lq;
                #pragma unroll
                for (int j = 0; j < 8; ++j) vf[j] = f2bf(vsrc[(size_t)j * DN]);
            }
            oacc[nt] = __builtin_amdgcn_mfma_f32_16x16x32_bf16(pf, vf, oacc[nt], 0, 0, 0);
        }
    }
    lsum += __shfl_xor(lsum, 16);
    lsum += __shfl_xor(lsum, 32);
    if (lg == 0) lred[wv * QB + lq] = lsum;
    __syncthreads();
    if (tid < QB) {
        float l = 0.f;
        #pragma unroll
        for (int w = 0; w < NWAVE; ++w) l += lred[w * QB + tid];
        lfin[tid] = 1.f / l;
    }
    __syncthreads();

    // ---- pass 3: stream p_attn = p'/l to global (coalesced float4 NT stores) ----
    #pragma unroll 1
    for (int q = 0; q < QB; ++q) {
        const float rl = lfin[q];
        bf16x4 s4 = *(const bf16x4*)&sbuf[q * SROW + tid * 4];
        f32x4 o;
        o[0] = bf2f(s4[0]) * rl; o[1] = bf2f(s4[1]) * rl;
        o[2] = bf2f(s4[2]) * rl; o[3] = bf2f(s4[3]) * rl;
        __builtin_nontemporal_store(o, (f32x4*)&out_p[(size_t)q * SN + tid * 4]);
    }
    __syncthreads();

    // ---- cross-wave O reduce (reuse sbuf memory), normalize, write ----
    float* obuf = (float*)sbuf;
    #pragma unroll
    for (int nt = 0; nt < 4; ++nt) {
        #pragma unroll
        for (int r = 0; r < 4; ++r)
            obuf[(wv * QB + 4 * lg + r) * DN + nt * 16 + lq] = oacc[nt][r];
    }
    __syncthreads();
    #pragma unroll
    for (int i = 0; i < 2; ++i) {
        const int idx = tid + i * 512;
        const int q = idx >> 6, d = idx & 63;
        float v = 0.f;
        #pragma unroll
        for (int w = 0; w < NWAVE; ++w) v += obuf[(w * QB + q) * DN + d];
        __builtin_nontemporal_store(v * lfin[q], &out_o[(size_t)q * DN + d]);
    }
}

extern "C" void kernel_launch(void* const* d_in, const int* in_sizes, int n_in,
                              void* d_out, int out_size, void* d_ws, size_t ws_size,
                              hipStream_t stream) {
    const float* Q = (const float*)d_in[0];
    const float* K = (const float*)d_in[1];
    const float* V = (const float*)d_in[2];
    const int*   M = (const int*)d_in[3];
    float* out = (float*)d_out;
    const size_t half = (size_t)BN * SN * DN;          // elements per buffer
    const size_t need = 2 * half * sizeof(short);      // 8 MB
    dim3 block(512);
    dim3 grid(BN * (SN / QB));                         // 2048 blocks
    if (ws_size >= need) {
        short* Kp = (short*)d_ws;
        short* Vt = Kp + half;
        prep_kv<<<dim3(BN * (SN / 64)), dim3(256), 0, stream>>>(K, V, Kp, Vt);
        attn_fused<1><<<grid, block, 0, stream>>>(Q, K, V, M, Kp, Vt, out);
    } else {
        attn_fused<0><<<grid, block, 0, stream>>>(Q, K, V, M, nullptr, nullptr, out);
    }
}